// Round 6
// baseline (81.555 us; speedup 1.0000x reference)
//
#include <hip/hip_runtime.h>

#define BATCH 4096
#define SEQ   80
#define EMBED 100
#define UNITS 64
#define NWG   (BATCH / 16)     // 256 waves, one 16-row batch tile each

typedef float f32x4  __attribute__((ext_vector_type(4)));
typedef short bf16x8 __attribute__((ext_vector_type(8)));

#define MFMA16 __builtin_amdgcn_mfma_f32_16x16x32_bf16

// ---- ws layout (bytes) ----
#define EMB_OFF 0u           // ushort[10000*128] = 2,560,000 B (zero-padded K)
#define W1T_OFF 2560000u     // ushort[64*128]
#define U1T_OFF 2576384u     // ushort[64*64]
#define W2T_OFF 2584576u
#define U2T_OFF 2592768u     // end ~2.6 MB (L2-resident)

__device__ __forceinline__ unsigned f2bfu(float f) {
    union { float f; unsigned u; } x; x.f = f;
    return (x.u + 0x7fffu + ((x.u >> 16) & 1u)) >> 16;   // RNE (prep only)
}
__device__ __forceinline__ unsigned cvtpk(float lo, float hi) {
    unsigned r;
    asm("v_cvt_pk_bf16_f32 %0, %1, %2" : "=v"(r) : "v"(lo), "v"(hi));
    return r;
}
// branch-free exact-tails tanh: 1 - 2/(e^{2x}+1). 5 instr, no abs/copysign.
__device__ __forceinline__ float fast_tanh(float x) {
    float e = __builtin_amdgcn_exp2f(x * 2.8853900817779268f);   // e^{2x}
    float r = __builtin_amdgcn_rcpf(e + 1.0f);
    return __builtin_fmaf(-2.0f, r, 1.0f);
}
// permuted unit assignment (R2/R3-verified): D slot (mt,reg) == B slot in-lane
__device__ __forceinline__ int uperm(int mt, int m15) {
    return 8 * (m15 >> 2) + 4 * (mt & 1) + (m15 & 3) + 32 * (mt >> 1);
}

// ---------------------------------------------------------------------------
// prep: bf16 tables — emb padded to K=128, transposed W1/U1/W2/U2.
// ---------------------------------------------------------------------------
__global__ __launch_bounds__(256) void prep_kernel(
    const float* __restrict__ emb, const float* __restrict__ W1,
    const float* __restrict__ U1,  const float* __restrict__ W2,
    const float* __restrict__ U2,  char* __restrict__ ws)
{
    ushort* emb_bf = (ushort*)(ws + EMB_OFF);
    ushort* w1t    = (ushort*)(ws + W1T_OFF);
    ushort* u1t    = (ushort*)(ws + U1T_OFF);
    ushort* w2t    = (ushort*)(ws + W2T_OFF);
    ushort* u2t    = (ushort*)(ws + U2T_OFF);
    const int tid    = blockIdx.x * 256 + threadIdx.x;
    const int stride = gridDim.x * 256;

    for (int i = tid; i < 10000 * 16; i += stride) {
        const int r = i >> 4, kc = (i & 15) * 8;
        unsigned w[4];
        #pragma unroll
        for (int p = 0; p < 4; ++p) {
            const int k0 = kc + 2 * p;
            unsigned lo = (k0     < EMBED) ? f2bfu(emb[r * EMBED + k0])     : 0u;
            unsigned hi = (k0 + 1 < EMBED) ? f2bfu(emb[r * EMBED + k0 + 1]) : 0u;
            w[p] = lo | (hi << 16);
        }
        uint4 v; v.x = w[0]; v.y = w[1]; v.z = w[2]; v.w = w[3];
        *(uint4*)(emb_bf + (size_t)r * 128 + kc) = v;
    }
    for (int i = tid; i < UNITS * 128; i += stride) {
        const int u = i >> 7, k = i & 127;
        w1t[i] = (k < EMBED) ? (ushort)f2bfu(W1[k * UNITS + u]) : (ushort)0;
    }
    for (int i = tid; i < UNITS * UNITS; i += stride) {
        const int u = i >> 6, k = i & 63;
        u1t[i] = (ushort)f2bfu(U1[k * UNITS + u]);
        w2t[i] = (ushort)f2bfu(W2[k * UNITS + u]);
        u2t[i] = (ushort)f2bfu(U2[k * UNITS + u]);
    }
}

// ---------------------------------------------------------------------------
// rnn: one wave per 16-row tile, FULL recurrence in registers. No LDS, no
// barriers. Per step, h2[t] and h1[t+1] both computed from {pb1,pb2}; the
// D->B handoff is in-lane cvt_pk (uperm layout, R3-verified).
// ---------------------------------------------------------------------------
__global__ __launch_bounds__(64, 1) void rnn_kernel(
    const int*   __restrict__ tokens,
    const float* __restrict__ b1,
    const float* __restrict__ b2,
    const float* __restrict__ Wo,
    const float* __restrict__ bo,
    float*       __restrict__ out,
    const char*  __restrict__ ws)
{
    const ushort* emb_bf = (const ushort*)(ws + EMB_OFF);
    const ushort* w1t    = (const ushort*)(ws + W1T_OFF);
    const ushort* u1t    = (const ushort*)(ws + U1T_OFF);
    const ushort* w2t    = (const ushort*)(ws + W2T_OFF);
    const ushort* u2t    = (const ushort*)(ws + U2T_OFF);

    const int lane = threadIdx.x;
    const int wg   = blockIdx.x;
    const int m15  = lane & 15;
    const int kgrp = lane >> 4;
    const long b80 = (long)(wg * 16 + m15) * SEQ;

    // weight A-frags: rows = uperm'd units, k standard (B comes out standard-k)
    bf16x8 aW1[4][4], aU1[4][2], aW2[4][2], aU2[4][2];
    #pragma unroll
    for (int mt = 0; mt < 4; ++mt) {
        const int u = uperm(mt, m15);
        #pragma unroll
        for (int ks = 0; ks < 4; ++ks)
            aW1[mt][ks] = *(const bf16x8*)(w1t + u * 128 + kgrp * 8 + 32 * ks);
        #pragma unroll
        for (int ks = 0; ks < 2; ++ks) {
            aU1[mt][ks] = *(const bf16x8*)(u1t + u * 64 + kgrp * 8 + 32 * ks);
            aW2[mt][ks] = *(const bf16x8*)(w2t + u * 64 + kgrp * 8 + 32 * ks);
            aU2[mt][ks] = *(const bf16x8*)(u2t + u * 64 + kgrp * 8 + 32 * ks);
        }
    }
    f32x4 b1c[4], b2c[4];
    #pragma unroll
    for (int mt = 0; mt < 4; ++mt) {
        const int ub = 8 * kgrp + 4 * (mt & 1) + 32 * (mt >> 1);
        b1c[mt] = *(const f32x4*)(b1 + ub);
        b2c[mt] = *(const f32x4*)(b2 + ub);
    }

    // ---- emb double-buffer prologue ----
    bf16x8 eX0, eX1, eX2, eX3, eY0, eY1, eY2, eY3;
    {
        const int tk0 = tokens[b80 + 0];
        const ushort* er = emb_bf + (size_t)tk0 * 128 + kgrp * 8;
        eX0 = *(const bf16x8*)(er);      eX1 = *(const bf16x8*)(er + 32);
        eX2 = *(const bf16x8*)(er + 64); eX3 = *(const bf16x8*)(er + 96);
    }
    {
        const int tk1 = tokens[b80 + 1];
        const ushort* er = emb_bf + (size_t)tk1 * 128 + kgrp * 8;
        eY0 = *(const bf16x8*)(er);      eY1 = *(const bf16x8*)(er + 32);
        eY2 = *(const bf16x8*)(er + 64); eY3 = *(const bf16x8*)(er + 96);
    }
    int tokX = tokens[b80 + 2];
    int tokY = tokens[b80 + 3];

    // register h-state as B-fragments
    uint4 pb1[2], pb2[2];
    pb2[0] = pb2[1] = uint4{0u, 0u, 0u, 0u};

    // ---- prologue: h1[0] = tanh(b1 + W1 emb[0]) ----
    {
        f32x4 d[4];
        #pragma unroll
        for (int mt = 0; mt < 4; ++mt) {
            f32x4 a = b1c[mt];
            a = MFMA16(aW1[mt][0], eX0, a, 0, 0, 0);
            a = MFMA16(aW1[mt][1], eX1, a, 0, 0, 0);
            a = MFMA16(aW1[mt][2], eX2, a, 0, 0, 0);
            a = MFMA16(aW1[mt][3], eX3, a, 0, 0, 0);
            d[mt] = a;
        }
        {   // refill X with emb[2]
            const ushort* er = emb_bf + (size_t)tokX * 128 + kgrp * 8;
            eX0 = *(const bf16x8*)(er);      eX1 = *(const bf16x8*)(er + 32);
            eX2 = *(const bf16x8*)(er + 64); eX3 = *(const bf16x8*)(er + 96);
        }
        tokX = tokens[b80 + 4];
        #pragma unroll
        for (int mt = 0; mt < 4; ++mt)
            #pragma unroll
            for (int r = 0; r < 4; ++r) d[mt][r] = fast_tanh(d[mt][r]);
        #pragma unroll
        for (int ks = 0; ks < 2; ++ks) {
            pb1[ks].x = cvtpk(d[2 * ks][0],     d[2 * ks][1]);
            pb1[ks].y = cvtpk(d[2 * ks][2],     d[2 * ks][3]);
            pb1[ks].z = cvtpk(d[2 * ks + 1][0], d[2 * ks + 1][1]);
            pb1[ks].w = cvtpk(d[2 * ks + 1][2], d[2 * ks + 1][3]);
        }
    }

    f32x4 d2[4];

// STEP T: h2[T] = tanh(b2 + W2 h1[T] + U2 h2[T-1]);
//         h1[T+1] = tanh(b1 + W1 emb[T+1] + U1 h1[T])   (emb tile in E slot)
#define STEPT(T, E0, E1, E2, E3, TOK)                                          \
  {                                                                            \
    f32x4 nd1[4], nd2[4];                                                      \
    _Pragma("unroll")                                                          \
    for (int mt = 0; mt < 4; ++mt) {                                           \
        f32x4 a = b1c[mt];                                                     \
        a = MFMA16(aW1[mt][0], E0, a, 0, 0, 0);                                \
        a = MFMA16(aW1[mt][1], E1, a, 0, 0, 0);                                \
        a = MFMA16(aW1[mt][2], E2, a, 0, 0, 0);                                \
        a = MFMA16(aW1[mt][3], E3, a, 0, 0, 0);                                \
        a = MFMA16(aU1[mt][0], *(const bf16x8*)&pb1[0], a, 0, 0, 0);           \
        a = MFMA16(aU1[mt][1], *(const bf16x8*)&pb1[1], a, 0, 0, 0);           \
        nd1[mt] = a;                                                           \
        f32x4 c = b2c[mt];                                                     \
        c = MFMA16(aW2[mt][0], *(const bf16x8*)&pb1[0], c, 0, 0, 0);           \
        c = MFMA16(aW2[mt][1], *(const bf16x8*)&pb1[1], c, 0, 0, 0);           \
        c = MFMA16(aU2[mt][0], *(const bf16x8*)&pb2[0], c, 0, 0, 0);           \
        c = MFMA16(aU2[mt][1], *(const bf16x8*)&pb2[1], c, 0, 0, 0);           \
        nd2[mt] = c;                                                           \
    }                                                                          \
    {   /* refill this slot with emb[T+3] (2-step lookahead, L2) */            \
        const ushort* er = emb_bf + (size_t)TOK * 128 + kgrp * 8;              \
        E0 = *(const bf16x8*)(er);      E1 = *(const bf16x8*)(er + 32);        \
        E2 = *(const bf16x8*)(er + 64); E3 = *(const bf16x8*)(er + 96);        \
    }                                                                          \
    TOK = tokens[b80 + ((T) + 5 < SEQ ? (T) + 5 : SEQ - 1)];                   \
    _Pragma("unroll")                                                          \
    for (int mt = 0; mt < 4; ++mt)                                             \
        _Pragma("unroll")                                                      \
        for (int r = 0; r < 4; ++r) {                                          \
            nd1[mt][r] = fast_tanh(nd1[mt][r]);                                \
            nd2[mt][r] = fast_tanh(nd2[mt][r]);                                \
        }                                                                      \
    _Pragma("unroll")                                                          \
    for (int ks = 0; ks < 2; ++ks) {                                           \
        pb1[ks].x = cvtpk(nd1[2 * ks][0],     nd1[2 * ks][1]);                 \
        pb1[ks].y = cvtpk(nd1[2 * ks][2],     nd1[2 * ks][3]);                 \
        pb1[ks].z = cvtpk(nd1[2 * ks + 1][0], nd1[2 * ks + 1][1]);             \
        pb1[ks].w = cvtpk(nd1[2 * ks + 1][2], nd1[2 * ks + 1][3]);             \
        pb2[ks].x = cvtpk(nd2[2 * ks][0],     nd2[2 * ks][1]);                 \
        pb2[ks].y = cvtpk(nd2[2 * ks][2],     nd2[2 * ks][3]);                 \
        pb2[ks].w = cvtpk(nd2[2 * ks + 1][2], nd2[2 * ks + 1][3]);             \
        pb2[ks].z = cvtpk(nd2[2 * ks + 1][0], nd2[2 * ks + 1][1]);             \
    }                                                                          \
    d2[0] = nd2[0]; d2[1] = nd2[1]; d2[2] = nd2[2]; d2[3] = nd2[3];            \
  }

    for (int t = 0; t < SEQ; t += 2) {
        STEPT(t,     eY0, eY1, eY2, eY3, tokY)   // uses emb[t+1]
        STEPT(t + 1, eX0, eX1, eX2, eX3, tokX)   // uses emb[t+2]
    }
#undef STEPT

    // ---- head: out[b] = sigmoid(h2[79] @ Wo + bo), permuted Wo gather ----
    float p = 0.f;
    #pragma unroll
    for (int mt = 0; mt < 4; ++mt) {
        f32x4 w = *(const f32x4*)(Wo + 8 * kgrp + 4 * (mt & 1) + 32 * (mt >> 1));
        p += d2[mt][0] * w.x + d2[mt][1] * w.y + d2[mt][2] * w.z + d2[mt][3] * w.w;
    }
    p += __shfl_xor(p, 16, 64);
    p += __shfl_xor(p, 32, 64);
    if (lane < 16) {
        const float z = p + bo[0];
        const float e = __builtin_amdgcn_exp2f(-z * 1.4426950408889634f);
        out[wg * 16 + lane] = __builtin_amdgcn_rcpf(1.0f + e);
    }
}

extern "C" void kernel_launch(void* const* d_in, const int* in_sizes, int n_in,
                              void* d_out, int out_size, void* d_ws, size_t ws_size,
                              hipStream_t stream) {
    const int*   tokens = (const int*)  d_in[0];
    const float* emb    = (const float*)d_in[1];
    const float* W1     = (const float*)d_in[2];
    const float* U1     = (const float*)d_in[3];
    const float* b1     = (const float*)d_in[4];
    const float* W2     = (const float*)d_in[5];
    const float* U2     = (const float*)d_in[6];
    const float* b2     = (const float*)d_in[7];
    const float* Wo     = (const float*)d_in[8];
    const float* bo     = (const float*)d_in[9];
    float* out = (float*)d_out;
    char*  ws  = (char*)d_ws;

    prep_kernel<<<640, 256, 0, stream>>>(emb, W1, U1, W2, U2, ws);
    rnn_kernel<<<NWG, 64, 0, stream>>>(tokens, b1, b2, Wo, bo, out, ws);
}